// Round 6
// baseline (233.961 us; speedup 1.0000x reference)
//
#include <hip/hip_runtime.h>

// Problem constants
#define NPTS 100000

constexpr int IB1 = 128;   // i-blocks per j-group in enc partial (512 blocks)
constexpr int SPB = 512;   // spart blocks (first SPB blocks of k_mid)
constexpr int GTB = 3125;  // gt blocks (remaining blocks of k_mid)

// Workspace layout (bytes), 16B-aligned
constexpr size_t OFF_PART  = 0;        // 32*128 f64 = 32768
constexpr size_t OFF_SACC  = 32768;    // 1024 f64   = 8192
constexpr size_t OFF_INVW2 = 40960;    // 512 f32    = 2048
constexpr size_t OFF_GT    = 43008;    // N*32 f32   = 12800000
// total ~12.85 MB

// ---------------------------------------------------------------------------
// D1: encoder matvec partials. part[j*128+ib] = partial of sum_i enc_w[j,i]*x[i].
// Block 0 also zeroes Sacc (visible to D2 via dispatch boundary).
__global__ __launch_bounds__(256) void k_enc_partial(
    const float* __restrict__ x, const float* __restrict__ enc_w,
    double* __restrict__ part, double* __restrict__ Sacc) {
  int tid = threadIdx.x;
  if (blockIdx.x == 0) {
    for (int q = tid; q < 1024; q += 256) Sacc[q] = 0.0;
  }
  int jg = blockIdx.x & 3;
  int ib = blockIdx.x >> 2;
  int j0 = jg * 8;
  double acc[8];
#pragma unroll
  for (int jj = 0; jj < 8; ++jj) acc[jj] = 0.0;
  for (int i = ib * 256 + tid; i < NPTS; i += IB1 * 256) {
    float xv = x[i];
#pragma unroll
    for (int jj = 0; jj < 8; ++jj)
      acc[jj] += (double)enc_w[(size_t)(j0 + jj) * NPTS + i] * (double)xv;
  }
#pragma unroll
  for (int jj = 0; jj < 8; ++jj) {
    double v = acc[jj];
#pragma unroll
    for (int off = 32; off >= 1; off >>= 1) v += __shfl_down(v, off);
    acc[jj] = v;
  }
  __shared__ double sw[4][8];
  int lane = tid & 63, w = tid >> 6;
  if (lane == 0)
    for (int jj = 0; jj < 8; ++jj) sw[w][jj] = acc[jj];
  __syncthreads();
  if (tid < 8) {
    double s = sw[0][tid] + sw[1][tid] + sw[2][tid] + sw[3][tid];
    part[(size_t)(j0 + tid) * IB1 + ib] = s;
  }
}

// ---------------------------------------------------------------------------
// D2: fused head + gT transpose + S-stripe + S-reduce (atomics into Sacc).
// Every block re-reduces part -> es[32] (32KB L2-broadcast, ~1us).
// Blocks [0,SPB): bw matvec -> invw2 LDS; S-stripe; f64 atomics into Sacc.
//   Block 0 also publishes invw2 to global for k_main.
// Blocks [SPB, SPB+GTB): gT[i*32+j] = (f32)es[j] * decoder[j*N+i].
__global__ __launch_bounds__(256) void k_mid(
    const float* __restrict__ decoder, const float* __restrict__ enc_b,
    const float* __restrict__ bw_w, const float* __restrict__ bw_b,
    const float* __restrict__ nd, const int* __restrict__ labels,
    const double* __restrict__ part, float* __restrict__ gT,
    float* __restrict__ invw2_g, double* __restrict__ Sacc) {
  __shared__ double es[32];
  __shared__ double sred[32][8];
  __shared__ float iw[512];       // spart path
  __shared__ float tile[32][33];  // gt path
  __shared__ float ef[32];
  int tid = threadIdx.x;
  // common: reduce part -> es
  {
    int j = tid >> 3, seg = tid & 7;
    double s = 0.0;
#pragma unroll
    for (int r = 0; r < 16; ++r) s += part[j * 128 + seg * 16 + r];
    sred[j][seg] = s;
  }
  __syncthreads();
  if (tid < 32) {
    double t = sred[tid][0];
#pragma unroll
    for (int q = 1; q < 8; ++q) t += sred[tid][q];
    es[tid] = t + (double)enc_b[tid];
  }
  __syncthreads();

  int b = blockIdx.x;
  if (b < SPB) {
    // head matvec -> iw (each thread: 2 rows of bw_w)
    for (int row = tid; row < 512; row += 256) {
      double wd = 0.0;
#pragma unroll 8
      for (int c = 0; c < 32; ++c) wd += (double)bw_w[row * 32 + c] * es[c];
      wd += (double)bw_b[row];
      int jr = row >> 4, m = row & 15;
      iw[m * 32 + jr] = (float)(1.0 / (wd * wd));
    }
    __syncthreads();
    if (b == 0) {
      for (int q = tid; q < 512; q += 256) invw2_g[q] = iw[q];
    }
    // S-stripe: thread = (j=tid>>3, kq=tid&7) owns k=kq*4..+3.
    int j = tid >> 3, kq = tid & 7;
    double a0 = 0.0, a1 = 0.0, a2 = 0.0, a3 = 0.0;
    int cnt = (NPTS - b + SPB - 1) / SPB;  // 195 or 196
    int full = cnt & ~15;
    for (int c0 = 0; c0 < full; c0 += 16) {
      float t0 = 0.0f, t1 = 0.0f, t2 = 0.0f, t3 = 0.0f;
#pragma unroll 4
      for (int c = 0; c < 16; ++c) {
        int i = b + (c0 + c) * SPB;
        int lab = labels[i];
        float icv = iw[lab * 32 + j];
        float4 d = *(const float4*)&nd[(size_t)i * 32 + kq * 4];
        t0 += fmaxf(fmaf(-(d.x * d.x), icv, 1.0f), 0.0f);
        t1 += fmaxf(fmaf(-(d.y * d.y), icv, 1.0f), 0.0f);
        t2 += fmaxf(fmaf(-(d.z * d.z), icv, 1.0f), 0.0f);
        t3 += fmaxf(fmaf(-(d.w * d.w), icv, 1.0f), 0.0f);
      }
      a0 += (double)t0; a1 += (double)t1; a2 += (double)t2; a3 += (double)t3;
    }
    {  // tail (<=15 iters)
      float t0 = 0.0f, t1 = 0.0f, t2 = 0.0f, t3 = 0.0f;
      for (int c = full; c < cnt; ++c) {
        int i = b + c * SPB;
        int lab = labels[i];
        float icv = iw[lab * 32 + j];
        float4 d = *(const float4*)&nd[(size_t)i * 32 + kq * 4];
        t0 += fmaxf(fmaf(-(d.x * d.x), icv, 1.0f), 0.0f);
        t1 += fmaxf(fmaf(-(d.y * d.y), icv, 1.0f), 0.0f);
        t2 += fmaxf(fmaf(-(d.z * d.z), icv, 1.0f), 0.0f);
        t3 += fmaxf(fmaf(-(d.w * d.w), icv, 1.0f), 0.0f);
      }
      a0 += (double)t0; a1 += (double)t1; a2 += (double)t2; a3 += (double)t3;
    }
    double* dst = &Sacc[j * 32 + kq * 4];
    unsafeAtomicAdd(dst + 0, a0);
    unsafeAtomicAdd(dst + 1, a1);
    unsafeAtomicAdd(dst + 2, a2);
    unsafeAtomicAdd(dst + 3, a3);
  } else {
    // gT transpose tile
    int gb = b - SPB;
    if (tid < 32) ef[tid] = (float)es[tid];
    int tx = tid & 31, ty = tid >> 5;
    int i0 = gb * 32;
    for (int jj = ty; jj < 32; jj += 8)
      tile[tx][jj] = decoder[(size_t)jj * NPTS + i0 + tx];
    __syncthreads();
    for (int ii = ty; ii < 32; ii += 8)
      gT[(size_t)(i0 + ii) * 32 + tx] = tile[ii][tx] * ef[tx];
  }
}

// ---------------------------------------------------------------------------
// D3: main gather. Prologue builds invS (f32, [k*32+j]) + invw2 copies in LDS
// from Sacc/invw2_g (written by D2; dispatch boundary = coherence). Then
// 4 points/wave, all 16 dwordx4 gathers in flight, f32 lane accum (partials
// ~1e-4 magnitude -> rounding ~1e-11), f64 cross-lane reduce.
__global__ __launch_bounds__(256, 4) void k_main(
    const float* __restrict__ nd, const int* __restrict__ nid,
    const int* __restrict__ labels, const float* __restrict__ gT,
    const float* __restrict__ invw2_g, const double* __restrict__ Sacc,
    float* __restrict__ out) {
  __shared__ __align__(16) float iwL[512];
  __shared__ __align__(16) float isL[1024];
  int tid = threadIdx.x;
#pragma unroll
  for (int u = 0; u < 2; ++u) iwL[tid + 256 * u] = invw2_g[tid + 256 * u];
#pragma unroll
  for (int u = 0; u < 4; ++u) {
    int t = tid * 4 + u;  // Sacc index = j*32+k
    int j = t >> 5, k = t & 31;
    isL[k * 32 + j] = (float)(1.0 / Sacc[t]);
  }
  __syncthreads();
  int lane = tid & 63;
  int w = tid >> 6;
  int q = lane & 7;   // j-quad: j = q*4..q*4+3
  int g = lane >> 3;  // k = kk*8+g
  int wv = blockIdx.x * 4 + w;  // 0..24999

  int id[4][4];
  float dvv[4][4];
  int lab[4];
#pragma unroll
  for (int p = 0; p < 4; ++p) {
    int i = wv + p * 25000;
    lab[p] = labels[i];
    int base = i * 32;
#pragma unroll
    for (int kk = 0; kk < 4; ++kk) {
      id[p][kk] = nid[base + kk * 8 + g];
      dvv[p][kk] = nd[base + kk * 8 + g];
    }
  }
  float4 gv[4][4];
#pragma unroll
  for (int p = 0; p < 4; ++p)
#pragma unroll
    for (int kk = 0; kk < 4; ++kk)
      gv[p][kk] = *(const float4*)&gT[(size_t)id[p][kk] * 32 + q * 4];
  float4 iwv[4];
#pragma unroll
  for (int p = 0; p < 4; ++p)
    iwv[p] = *(const float4*)&iwL[lab[p] * 32 + q * 4];
  float4 sv[4];
#pragma unroll
  for (int kk = 0; kk < 4; ++kk)
    sv[kk] = *(const float4*)&isL[(kk * 8 + g) * 32 + q * 4];

  double a[4];
#pragma unroll
  for (int p = 0; p < 4; ++p) {
    float ap = 0.0f;
#pragma unroll
    for (int kk = 0; kk < 4; ++kk) {
      float md = -dvv[p][kk] * dvv[p][kk];
      float u0 = fmaxf(fmaf(md, iwv[p].x, 1.0f), 0.0f);
      float u1 = fmaxf(fmaf(md, iwv[p].y, 1.0f), 0.0f);
      float u2 = fmaxf(fmaf(md, iwv[p].z, 1.0f), 0.0f);
      float u3 = fmaxf(fmaf(md, iwv[p].w, 1.0f), 0.0f);
      ap += gv[p][kk].x * (u0 * sv[kk].x);
      ap += gv[p][kk].y * (u1 * sv[kk].y);
      ap += gv[p][kk].z * (u2 * sv[kk].z);
      ap += gv[p][kk].w * (u3 * sv[kk].w);
    }
    a[p] = (double)ap;
  }
#pragma unroll
  for (int off = 32; off >= 1; off >>= 1) {
#pragma unroll
    for (int p = 0; p < 4; ++p) a[p] += __shfl_down(a[p], off);
  }
  if (lane == 0) {
#pragma unroll
    for (int p = 0; p < 4; ++p) out[wv + p * 25000] = (float)a[p];
  }
}

// ---------------------------------------------------------------------------
extern "C" void kernel_launch(void* const* d_in, const int* in_sizes, int n_in,
                              void* d_out, int out_size, void* d_ws,
                              size_t ws_size, hipStream_t stream) {
  const float* x       = (const float*)d_in[0];
  const float* enc_w   = (const float*)d_in[1];
  const float* enc_b   = (const float*)d_in[2];
  const float* decoder = (const float*)d_in[3];
  const float* bw_w    = (const float*)d_in[4];
  const float* bw_b    = (const float*)d_in[5];
  const float* nd      = (const float*)d_in[6];
  const int*   nid     = (const int*)d_in[7];
  const int*   labels  = (const int*)d_in[8];
  float* out = (float*)d_out;

  char* ws = (char*)d_ws;
  double* part  = (double*)(ws + OFF_PART);
  double* Sacc  = (double*)(ws + OFF_SACC);
  float*  invw2 = (float*)(ws + OFF_INVW2);
  float*  gT    = (float*)(ws + OFF_GT);

  hipLaunchKernelGGL(k_enc_partial, dim3(512), dim3(256), 0, stream,
                     x, enc_w, part, Sacc);
  hipLaunchKernelGGL(k_mid, dim3(SPB + GTB), dim3(256), 0, stream,
                     decoder, enc_b, bw_w, bw_b, nd, labels, part, gT, invw2, Sacc);
  hipLaunchKernelGGL(k_main, dim3(6250), dim3(256), 0, stream,
                     nd, nid, labels, gT, invw2, Sacc, out);
}

// Round 7
// 161.315 us; speedup vs baseline: 1.4503x; 1.4503x over previous
//
#include <hip/hip_runtime.h>

// Problem constants
#define NPTS 100000

constexpr int IB1  = 128;   // i-blocks per j-group in enc partial (512 blocks)
constexpr int SPB2 = 1536;  // spart blocks (first SPB2 blocks of k_gtspart)
constexpr int GTB  = 3125;  // gt blocks (remaining blocks of k_gtspart)

typedef _Float16 half_t;
typedef _Float16 half4 __attribute__((ext_vector_type(4)));

// Workspace layout (bytes), 16B-aligned
constexpr size_t OFF_PART   = 0;         // 32*128 f64  = 32768
constexpr size_t OFF_ENC    = 32768;     // 32 f64      = 256
constexpr size_t OFF_INVW2  = 33024;     // 512 f32     = 2048
constexpr size_t OFF_SACC   = 35072;     // 1024 f64    = 8192
constexpr size_t OFF_SPARTF = 43264;     // 1536*1024 f32 = 6291456
constexpr size_t OFF_GTH    = 6334720;   // N*32 f16    = 6400000
// total ~12.73 MB

// ---------------------------------------------------------------------------
// D1: encoder matvec partials. part[j*128+ib] = partial of sum_i enc_w[j,i]*x[i].
// Block 0 also zeroes Sacc (visible to later dispatches via dispatch boundary).
__global__ __launch_bounds__(256) void k_enc_partial(
    const float* __restrict__ x, const float* __restrict__ enc_w,
    double* __restrict__ part, double* __restrict__ Sacc) {
  int tid = threadIdx.x;
  if (blockIdx.x == 0) {
    for (int q = tid; q < 1024; q += 256) Sacc[q] = 0.0;
  }
  int jg = blockIdx.x & 3;
  int ib = blockIdx.x >> 2;
  int j0 = jg * 8;
  double acc[8];
#pragma unroll
  for (int jj = 0; jj < 8; ++jj) acc[jj] = 0.0;
  for (int i = ib * 256 + tid; i < NPTS; i += IB1 * 256) {
    float xv = x[i];
#pragma unroll
    for (int jj = 0; jj < 8; ++jj)
      acc[jj] += (double)enc_w[(size_t)(j0 + jj) * NPTS + i] * (double)xv;
  }
#pragma unroll
  for (int jj = 0; jj < 8; ++jj) {
    double v = acc[jj];
#pragma unroll
    for (int off = 32; off >= 1; off >>= 1) v += __shfl_down(v, off);
    acc[jj] = v;
  }
  __shared__ double sw[4][8];
  int lane = tid & 63, w = tid >> 6;
  if (lane == 0)
    for (int jj = 0; jj < 8; ++jj) sw[w][jj] = acc[jj];
  __syncthreads();
  if (tid < 8) {
    double s = sw[0][tid] + sw[1][tid] + sw[2][tid] + sw[3][tid];
    part[(size_t)(j0 + tid) * IB1 + ib] = s;
  }
}

// ---------------------------------------------------------------------------
// D2: reduce part -> encoded; bandwidths = bw_w@enc + bw_b; invw2[m*32+j]=1/w^2.
// One block, 512 threads.
__global__ __launch_bounds__(512) void k_head(
    const double* __restrict__ part, const float* __restrict__ enc_b,
    const float* __restrict__ bw_w, const float* __restrict__ bw_b,
    double* __restrict__ enc_out, float* __restrict__ invw2) {
  __shared__ double es[32];
  __shared__ double sred[32][16];
  int tid = threadIdx.x;
  int j = tid >> 4, slot = tid & 15;
  double s = 0.0;
#pragma unroll
  for (int r = 0; r < 8; ++r) s += part[j * 128 + slot * 8 + r];
  sred[j][slot] = s;
  __syncthreads();
  if (tid < 32) {
    double t = 0.0;
    for (int q = 0; q < 16; ++q) t += sred[tid][q];
    t += (double)enc_b[tid];
    enc_out[tid] = t;
    es[tid] = t;
  }
  __syncthreads();
  double wd = 0.0;
  for (int c = 0; c < 32; ++c) wd += (double)bw_w[tid * 32 + c] * es[c];
  wd += (double)bw_b[tid];
  int jr = tid >> 4, m = tid & 15;
  invw2[m * 32 + jr] = (float)(1.0 / (wd * wd));
}

// ---------------------------------------------------------------------------
// D3: fused (no shared prologue — head results come from global).
// Blocks [0,SPB2): S-stripe -> f32 partials spartf[b*1024 + j*32 + k].
// Blocks [SPB2, SPB2+GTB): gTh[i*32+j] = (f16)((f32)enc[j] * decoder[j*N+i]).
__global__ __launch_bounds__(256) void k_gtspart(
    const float* __restrict__ decoder, const double* __restrict__ enc,
    const float* __restrict__ nd, const int* __restrict__ labels,
    const float* __restrict__ invw2_g, float* __restrict__ spartf,
    half_t* __restrict__ gTh) {
  int tid = threadIdx.x;
  int b = blockIdx.x;
  if (b < SPB2) {
    __shared__ float iw[512];
    for (int q = tid; q < 512; q += 256) iw[q] = invw2_g[q];
    __syncthreads();
    int j = tid >> 3, kq = tid & 7;
    float t0 = 0.0f, t1 = 0.0f, t2 = 0.0f, t3 = 0.0f;
    int cnt = (NPTS - b + SPB2 - 1) / SPB2;  // 65 or 66
#pragma unroll 4
    for (int c = 0; c < cnt; ++c) {
      int i = b + c * SPB2;
      int lab = labels[i];
      float icv = iw[lab * 32 + j];
      float4 d = *(const float4*)&nd[(size_t)i * 32 + kq * 4];
      t0 += fmaxf(fmaf(-(d.x * d.x), icv, 1.0f), 0.0f);
      t1 += fmaxf(fmaf(-(d.y * d.y), icv, 1.0f), 0.0f);
      t2 += fmaxf(fmaf(-(d.z * d.z), icv, 1.0f), 0.0f);
      t3 += fmaxf(fmaf(-(d.w * d.w), icv, 1.0f), 0.0f);
    }
    float4 v = make_float4(t0, t1, t2, t3);
    *(float4*)&spartf[(size_t)b * 1024 + j * 32 + kq * 4] = v;
  } else {
    __shared__ float tile[32][33];
    __shared__ float ef[32];
    int gb = b - SPB2;
    if (tid < 32) ef[tid] = (float)enc[tid];
    int tx = tid & 31, ty = tid >> 5;
    int i0 = gb * 32;
    for (int jj = ty; jj < 32; jj += 8)
      tile[tx][jj] = decoder[(size_t)jj * NPTS + i0 + tx];
    __syncthreads();
    for (int ii = ty; ii < 32; ii += 8)
      gTh[(size_t)(i0 + ii) * 32 + tx] = (half_t)(tile[ii][tx] * ef[tx]);
  }
}

// ---------------------------------------------------------------------------
// D4: reduce spartf columns -> Sacc (f64 atomics, depth 16/address).
// 64 blocks x 256: gt=(jk 0..1023, seg 0..15); each thread sums 96 rows.
__global__ __launch_bounds__(256) void k_sred(
    const float* __restrict__ spartf, double* __restrict__ Sacc) {
  int gt = blockIdx.x * 256 + threadIdx.x;  // 0..16383
  int jk = gt & 1023;
  int seg = gt >> 10;  // 0..15
  double s = 0.0;
#pragma unroll 8
  for (int r = 0; r < SPB2 / 16; ++r)
    s += (double)spartf[(size_t)(seg * (SPB2 / 16) + r) * 1024 + jk];
  unsafeAtomicAdd(&Sacc[jk], s);
}

// ---------------------------------------------------------------------------
// D5: main gather. Prologue builds invS (f32, [k*32+j]) and invw2 in LDS.
// 4 points/wave; lane l: q=l&7 -> j quad, g=l>>3 -> k=kk*8+g. All 16 gathers
// (f16, 8B/lane, 64B/line) issued before use; f32 lane accum; f64 reduce.
__global__ __launch_bounds__(256, 4) void k_main(
    const float* __restrict__ nd, const int* __restrict__ nid,
    const int* __restrict__ labels, const half_t* __restrict__ gTh,
    const float* __restrict__ invw2_g, const double* __restrict__ Sacc,
    float* __restrict__ out) {
  __shared__ __align__(16) float iwL[512];
  __shared__ __align__(16) float isL[1024];
  int tid = threadIdx.x;
#pragma unroll
  for (int u = 0; u < 2; ++u) iwL[tid + 256 * u] = invw2_g[tid + 256 * u];
#pragma unroll
  for (int u = 0; u < 4; ++u) {
    int t = tid * 4 + u;  // Sacc index = j*32+k
    int j = t >> 5, k = t & 31;
    isL[k * 32 + j] = 1.0f / (float)Sacc[t];
  }
  __syncthreads();
  int lane = tid & 63;
  int w = tid >> 6;
  int q = lane & 7;   // j-quad: j = q*4..q*4+3
  int g = lane >> 3;  // k = kk*8+g
  int wv = blockIdx.x * 4 + w;  // 0..24999

  int id[4][4];
  float dvv[4][4];
  int lab[4];
#pragma unroll
  for (int p = 0; p < 4; ++p) {
    int i = wv + p * 25000;
    lab[p] = labels[i];
    int base = i * 32;
#pragma unroll
    for (int kk = 0; kk < 4; ++kk) {
      id[p][kk] = nid[base + kk * 8 + g];
      dvv[p][kk] = nd[base + kk * 8 + g];
    }
  }
  half4 gv[4][4];
#pragma unroll
  for (int p = 0; p < 4; ++p)
#pragma unroll
    for (int kk = 0; kk < 4; ++kk)
      gv[p][kk] = *(const half4*)&gTh[(size_t)id[p][kk] * 32 + q * 4];
  float4 iwv[4];
#pragma unroll
  for (int p = 0; p < 4; ++p)
    iwv[p] = *(const float4*)&iwL[lab[p] * 32 + q * 4];
  float4 sv[4];
#pragma unroll
  for (int kk = 0; kk < 4; ++kk)
    sv[kk] = *(const float4*)&isL[(kk * 8 + g) * 32 + q * 4];

  double a[4];
#pragma unroll
  for (int p = 0; p < 4; ++p) {
    float ap = 0.0f;
#pragma unroll
    for (int kk = 0; kk < 4; ++kk) {
      float md = -dvv[p][kk] * dvv[p][kk];
      float u0 = fmaxf(fmaf(md, iwv[p].x, 1.0f), 0.0f);
      float u1 = fmaxf(fmaf(md, iwv[p].y, 1.0f), 0.0f);
      float u2 = fmaxf(fmaf(md, iwv[p].z, 1.0f), 0.0f);
      float u3 = fmaxf(fmaf(md, iwv[p].w, 1.0f), 0.0f);
      ap += (float)gv[p][kk].x * (u0 * sv[kk].x);
      ap += (float)gv[p][kk].y * (u1 * sv[kk].y);
      ap += (float)gv[p][kk].z * (u2 * sv[kk].z);
      ap += (float)gv[p][kk].w * (u3 * sv[kk].w);
    }
    a[p] = (double)ap;
  }
#pragma unroll
  for (int off = 32; off >= 1; off >>= 1) {
#pragma unroll
    for (int p = 0; p < 4; ++p) a[p] += __shfl_down(a[p], off);
  }
  if (lane == 0) {
#pragma unroll
    for (int p = 0; p < 4; ++p) out[wv + p * 25000] = (float)a[p];
  }
}

// ---------------------------------------------------------------------------
extern "C" void kernel_launch(void* const* d_in, const int* in_sizes, int n_in,
                              void* d_out, int out_size, void* d_ws,
                              size_t ws_size, hipStream_t stream) {
  const float* x       = (const float*)d_in[0];
  const float* enc_w   = (const float*)d_in[1];
  const float* enc_b   = (const float*)d_in[2];
  const float* decoder = (const float*)d_in[3];
  const float* bw_w    = (const float*)d_in[4];
  const float* bw_b    = (const float*)d_in[5];
  const float* nd      = (const float*)d_in[6];
  const int*   nid     = (const int*)d_in[7];
  const int*   labels  = (const int*)d_in[8];
  float* out = (float*)d_out;

  char* ws = (char*)d_ws;
  double* part   = (double*)(ws + OFF_PART);
  double* enc_d  = (double*)(ws + OFF_ENC);
  float*  invw2  = (float*)(ws + OFF_INVW2);
  double* Sacc   = (double*)(ws + OFF_SACC);
  float*  spartf = (float*)(ws + OFF_SPARTF);
  half_t* gTh    = (half_t*)(ws + OFF_GTH);

  hipLaunchKernelGGL(k_enc_partial, dim3(512), dim3(256), 0, stream,
                     x, enc_w, part, Sacc);
  hipLaunchKernelGGL(k_head, dim3(1), dim3(512), 0, stream,
                     part, enc_b, bw_w, bw_b, enc_d, invw2);
  hipLaunchKernelGGL(k_gtspart, dim3(SPB2 + GTB), dim3(256), 0, stream,
                     decoder, enc_d, nd, labels, invw2, spartf, gTh);
  hipLaunchKernelGGL(k_sred, dim3(64), dim3(256), 0, stream, spartf, Sacc);
  hipLaunchKernelGGL(k_main, dim3(6250), dim3(256), 0, stream,
                     nd, nid, labels, gTh, invw2, Sacc, out);
}